// Round 6
// baseline (5511.316 us; speedup 1.0000x reference)
//
#include <hip/hip_runtime.h>
#include <cmath>

// ---- problem dims (fixed per reference) ----
#define YCH 8        // y_channels
#define NTR 16       // trials
#define LLEN 4096    // trial length
#define CK  16       // kernels per channel
#define KS  64       // kernel size
#define ENC 4033     // LLEN - KS + 1
#define NP  128      // YCH*NTR independent problems
#define INV_LIP 0.1f     // 1/10
#define THRESH 0.01f     // LAM/LIP = 0.1/10

#define TI 512           // x outputs per block tile
#define BW 640           // B slab width: [i0-64, i0+576)
#define RW 576           // res width:    [i0, i0+576)
#define RWP 580          // padded res pitch

// B over [gi4, gi4+3], zero outside [0, ENC):  B = a + gamma*(a - p)
__device__ __forceinline__ float4 loadB4(const float* __restrict__ A,
                                         const float* __restrict__ P,
                                         float gamma, size_t coff, int gi4)
{
    if (gi4 >= 0 && gi4 + 3 < ENC) {
        float4 a = *(const float4*)(A + coff + gi4);
        float4 p = *(const float4*)(P + coff + gi4);
        return make_float4(fmaf(gamma, a.x - p.x, a.x),
                           fmaf(gamma, a.y - p.y, a.y),
                           fmaf(gamma, a.z - p.z, a.z),
                           fmaf(gamma, a.w - p.w, a.w));
    }
    float r[4];
    #pragma unroll
    for (int j = 0; j < 4; ++j) {
        int gi = gi4 + j;
        if (gi >= 0 && gi < ENC) {
            float a = A[coff + gi], p = P[coff + gi];
            r[j] = fmaf(gamma, a - p, a);
        } else r[j] = 0.f;
    }
    return make_float4(r[0], r[1], r[2], r[3]);
}

// =====================================================================
// fista_step: one FULL FISTA iteration per launch.
//   phase 1: stage B tile (16ch x 640) + res=y tile + H into LDS
//   phase 2: synthesis conv (wave w -> channels 4w..4w+3), rs -= partial
//   phase 3: analysis conv + soft-threshold, B-term from LDS, write Anext
// block = (itile, p); 256 thr (4 waves); grid (8, 128).
// =====================================================================
__global__ __launch_bounds__(256, 3) void fista_step(
    const float* __restrict__ y, const float* __restrict__ H,
    const float* __restrict__ Acur, const float* __restrict__ Aprev,
    float gamma, int first, float* __restrict__ Anext)
{
    __shared__ __align__(16) float Bs[CK * BW];   // 40960 B
    __shared__ __align__(16) float rs[RWP];       //  2320 B
    __shared__ __align__(16) float hs[CK * KS];   //  4096 B

    const int tid = threadIdx.x;
    const int i0  = blockIdx.x * TI;
    const int p   = blockIdx.y;
    const int n = p & 15, ch = p >> 4;

    // ---- phase 1: staging ----
    ((float4*)hs)[tid] = ((const float4*)(H + (size_t)ch * CK * KS))[tid]; // 256 f4

    const float* ybase = y + ((size_t)n * YCH + ch) * LLEN;
    if (tid < RW / 4) {
        int gi = i0 + 4 * tid;
        float4 v;
        if (gi + 3 < LLEN) v = *(const float4*)(ybase + gi);
        else {
            float r[4];
            #pragma unroll
            for (int j = 0; j < 4; ++j) r[j] = (gi + j < LLEN) ? ybase[gi + j] : 0.f;
            v = make_float4(r[0], r[1], r[2], r[3]);
        }
        ((float4*)rs)[tid] = v;
    }

    const size_t pbase = (size_t)p * CK * ENC;
    if (!first) {
        // 16 ch x 160 f4 = 2560 f4 = 10 per thread
        #pragma unroll
        for (int s = 0; s < 10; ++s) {
            int F  = tid + 256 * s;
            int c  = F / (BW / 4);
            int l4 = F - c * (BW / 4);
            ((float4*)Bs)[F] =
                loadB4(Acur, Aprev, gamma, pbase + (size_t)c * ENC, i0 - 64 + 4 * l4);
        }
    }
    __syncthreads();

    const int wv = tid >> 6, l = tid & 63;

    // ---- phase 2: synthesis conv, rs[lr] -= sum_{c in wave,k} B[c,lr+64-k]h[c,k]
    if (!first) {
        float a0[4] = {0.f,0.f,0.f,0.f};
        float a1[4] = {0.f,0.f,0.f,0.f};
        float a2[4] = {0.f,0.f,0.f,0.f};
        for (int cc = 0; cc < 4; ++cc) {
            const int c = 4 * wv + cc;
            const float* Bb = Bs + c * BW;
            const float4* hb = (const float4*)(hs + c * KS);

            // group 0: lr0 = 4l; group 1: lr0 = 256+4l; group 2 (l<16): 512+4l
            {
                float wf[68];
                const float4* src = (const float4*)(Bb + 4 * l);
                #pragma unroll
                for (int q = 0; q < 17; ++q) {
                    float4 v = src[q];
                    wf[4*q] = v.x; wf[4*q+1] = v.y; wf[4*q+2] = v.z; wf[4*q+3] = v.w;
                }
                #pragma unroll
                for (int kg = 0; kg < 16; ++kg) {
                    float4 h4 = hb[kg];
                    float hh[4] = {h4.x, h4.y, h4.z, h4.w};
                    #pragma unroll
                    for (int m = 0; m < 4; ++m) {
                        const int k = 4 * kg + m;
                        #pragma unroll
                        for (int j = 0; j < 4; ++j)
                            a0[j] = fmaf(wf[j + 64 - k], hh[m], a0[j]);
                    }
                }
            }
            {
                float wf[68];
                const float4* src = (const float4*)(Bb + 256 + 4 * l);
                #pragma unroll
                for (int q = 0; q < 17; ++q) {
                    float4 v = src[q];
                    wf[4*q] = v.x; wf[4*q+1] = v.y; wf[4*q+2] = v.z; wf[4*q+3] = v.w;
                }
                #pragma unroll
                for (int kg = 0; kg < 16; ++kg) {
                    float4 h4 = hb[kg];
                    float hh[4] = {h4.x, h4.y, h4.z, h4.w};
                    #pragma unroll
                    for (int m = 0; m < 4; ++m) {
                        const int k = 4 * kg + m;
                        #pragma unroll
                        for (int j = 0; j < 4; ++j)
                            a1[j] = fmaf(wf[j + 64 - k], hh[m], a1[j]);
                    }
                }
            }
            if (l < 16) {
                float wf[68];
                const float4* src = (const float4*)(Bb + 512 + 4 * l);
                #pragma unroll
                for (int q = 0; q < 17; ++q) {
                    float4 v = src[q];
                    wf[4*q] = v.x; wf[4*q+1] = v.y; wf[4*q+2] = v.z; wf[4*q+3] = v.w;
                }
                #pragma unroll
                for (int kg = 0; kg < 16; ++kg) {
                    float4 h4 = hb[kg];
                    float hh[4] = {h4.x, h4.y, h4.z, h4.w};
                    #pragma unroll
                    for (int m = 0; m < 4; ++m) {
                        const int k = 4 * kg + m;
                        #pragma unroll
                        for (int j = 0; j < 4; ++j)
                            a2[j] = fmaf(wf[j + 64 - k], hh[m], a2[j]);
                    }
                }
            }
        }
        #pragma unroll
        for (int j = 0; j < 4; ++j) atomicAdd(&rs[4*l + j],       -a0[j]);
        #pragma unroll
        for (int j = 0; j < 4; ++j) atomicAdd(&rs[256 + 4*l + j], -a1[j]);
        if (l < 16) {
            #pragma unroll
            for (int j = 0; j < 4; ++j) atomicAdd(&rs[512 + 4*l + j], -a2[j]);
        }
        __syncthreads();
    }

    // ---- phase 3: analysis conv + update. lane owns i = i0+8l..+7,
    //      wave wv handles channels 4wv..4wv+3 (window reused across them).
    float wf[72];
    {
        const float4* rr = (const float4*)(rs + 8 * l);
        #pragma unroll
        for (int q = 0; q < 18; ++q) {
            float4 v = rr[q];
            wf[4*q] = v.x; wf[4*q+1] = v.y; wf[4*q+2] = v.z; wf[4*q+3] = v.w;
        }
    }

    const int i = i0 + 8 * l;
    for (int cc = 0; cc < 4; ++cc) {
        const int c = 4 * wv + cc;
        float acc[8] = {0.f,0.f,0.f,0.f,0.f,0.f,0.f,0.f};
        const float4* hb = (const float4*)(hs + c * KS);
        #pragma unroll
        for (int kg = 0; kg < 16; ++kg) {
            float4 h4 = hb[kg];
            float hh[4] = {h4.x, h4.y, h4.z, h4.w};
            #pragma unroll
            for (int m = 0; m < 4; ++m) {
                const int k = 4 * kg + m;
                #pragma unroll
                for (int j = 0; j < 8; ++j)
                    acc[j] = fmaf(wf[k + j], hh[m], acc[j]);
            }
        }

        const size_t idx = pbase + (size_t)c * ENC + i;
        const float* Bb = Bs + c * BW + 64 + 8 * l;
        if (i + 7 < ENC) {
            float o[8];
            #pragma unroll
            for (int j = 0; j < 8; ++j) {
                float B = first ? 0.f : Bb[j];
                o[j] = fmaxf(fmaf(acc[j], INV_LIP, B) - THRESH, 0.f);
            }
            *(float4*)(Anext + idx)     = make_float4(o[0], o[1], o[2], o[3]);
            *(float4*)(Anext + idx + 4) = make_float4(o[4], o[5], o[6], o[7]);
        } else {
            #pragma unroll
            for (int j = 0; j < 8; ++j) {
                if (i + j < ENC) {
                    float B = first ? 0.f : Bb[j];
                    Anext[idx + j] = fmaxf(fmaf(acc[j], INV_LIP, B) - THRESH, 0.f);
                }
            }
        }
    }
}

// =====================================================================
extern "C" void kernel_launch(void* const* d_in, const int* in_sizes, int n_in,
                              void* d_out, int out_size, void* d_ws, size_t ws_size,
                              hipStream_t stream)
{
    const float* y = (const float*)d_in[0];   // [NTR, YCH, LLEN]
    const float* H = (const float*)d_in[1];   // [YCH, CK, 1, KS]

    float* bufA = (float*)d_ws;               // A_t for even t
    float* bufB = (float*)d_out;              // A_t for odd t (A9 -> d_out)

    double s[11]; s[0] = 1.0;
    for (int t = 1; t <= 10; ++t) s[t] = 0.5 * (1.0 + sqrt(1.0 + 4.0 * s[t-1] * s[t-1]));

    dim3 grid(8, NP);

    for (int t = 0; t < 10; ++t) {
        float gamma = (t == 0) ? 0.f : (float)((s[t-1] - 1.0) / s[t]);
        float* Anext       = (t & 1) ? bufB : bufA;
        const float* Acur  = (t & 1) ? bufA : bufB;              // A_{t-1}
        const float* Aprev = (t <= 1) ? Acur                     // gamma==0, unused
                                      : ((t & 1) ? bufB : bufA); // A_{t-2}
        fista_step<<<grid, 256, 0, stream>>>(y, H, Acur, Aprev, gamma,
                                             (t == 0) ? 1 : 0, Anext);
    }
}

// Round 7
// 665.020 us; speedup vs baseline: 8.2875x; 8.2875x over previous
//
#include <hip/hip_runtime.h>
#include <cmath>

// ---- problem dims (fixed per reference) ----
#define YCH 8        // y_channels
#define NTR 16       // trials
#define LLEN 4096    // trial length
#define CK  16       // kernels per channel
#define KS  64       // kernel size
#define ENC 4033     // LLEN - KS + 1
#define NP  128      // YCH*NTR independent problems
#define INV_LIP 0.1f     // 1/10
#define THRESH 0.01f     // LAM/LIP = 0.1/10

#define XW4 272          // float4s per 1088-float window tile

// B over [gi4, gi4+3], zero outside [0, ENC):  B = a + gamma*(a - p)
__device__ __forceinline__ float4 loadB4(const float* __restrict__ A,
                                         const float* __restrict__ P,
                                         float gamma, size_t coff, int gi4)
{
    if (gi4 >= 0 && gi4 + 3 < ENC) {
        float4 a = *(const float4*)(A + coff + gi4);
        float4 p = *(const float4*)(P + coff + gi4);
        return make_float4(fmaf(gamma, a.x - p.x, a.x),
                           fmaf(gamma, a.y - p.y, a.y),
                           fmaf(gamma, a.z - p.z, a.z),
                           fmaf(gamma, a.w - p.w, a.w));
    }
    float r[4];
    #pragma unroll
    for (int j = 0; j < 4; ++j) {
        int gi = gi4 + j;
        if (gi >= 0 && gi < ENC) {
            float a = A[coff + gi], p = P[coff + gi];
            r[j] = fmaf(gamma, a - p, a);
        } else r[j] = 0.f;
    }
    return make_float4(r[0], r[1], r[2], r[3]);
}

// =====================================================================
// resid_quad: part[q][p][t] = sum_{c in quad q, k} B[p,c,t-k]*H[ch,c,k]
// Structure cloned from fista_quad (the proven ~2.6us shape):
//   stage quad's 4 B-windows (momentum folded) into LDS, ONE barrier,
//   then per channel: hoist wf[68] (one live at a time), 256 FMA instr.
// block = (ttile=1024, q, p) -> grid 2048 x 256 thr.
// =====================================================================
__global__ __launch_bounds__(256) void resid_quad(
    const float* __restrict__ H,
    const float* __restrict__ Acur, const float* __restrict__ Aprev,
    float gamma, float* __restrict__ part)
{
    __shared__ __align__(16) float xs[4 * 1088];  // 17408 B
    __shared__ __align__(16) float hs[4 * KS];    //  1024 B
    const int tid = threadIdx.x;
    const int t0  = blockIdx.x * 1024;
    const int c0  = blockIdx.y * 4;
    const int p   = blockIdx.z;
    const int ch  = p >> 4;

    if (tid < 64)
        ((float4*)hs)[tid] = ((const float4*)(H + ((size_t)ch * CK + c0) * KS))[tid];

    const size_t pbase = (size_t)p * CK * ENC;
    // stage 4 channels x 272 f4 = 1088 f4 (4.25 per thread)
    #pragma unroll
    for (int s = 0; s < 5; ++s) {
        int l4 = tid + 256 * s;
        if (l4 < 4 * XW4) {
            int c   = l4 / XW4;          // compile-time const divisor
            int off = l4 - c * XW4;
            ((float4*)xs)[l4] = loadB4(Acur, Aprev, gamma,
                                       pbase + (size_t)(c0 + c) * ENC,
                                       t0 - 64 + 4 * off);
        }
    }
    __syncthreads();

    float acc[4] = {0.f, 0.f, 0.f, 0.f};

    for (int cc = 0; cc < 4; ++cc) {
        // window wf[68] = xs[c][4*tid .. 4*tid+67]; output t = t0+4*tid+j
        float wf[68];
        const float4* xr = (const float4*)(xs + cc * 1088) + tid;
        #pragma unroll
        for (int q = 0; q < 17; ++q) {
            float4 v = xr[q];
            wf[4*q] = v.x; wf[4*q+1] = v.y; wf[4*q+2] = v.z; wf[4*q+3] = v.w;
        }
        const float4* hc = (const float4*)(hs + cc * KS);
        #pragma unroll
        for (int g = 0; g < 16; ++g) {
            float4 h4 = hc[g];
            float hh[4] = {h4.x, h4.y, h4.z, h4.w};
            #pragma unroll
            for (int m = 0; m < 4; ++m) {
                const int k = 4 * g + m;          // tap index
                #pragma unroll
                for (int j = 0; j < 4; ++j)       // local idx = 64 + j - k
                    acc[j] = fmaf(wf[64 + j - k], hh[m], acc[j]);
            }
        }
    }

    const int t = t0 + 4 * tid;
    *(float4*)(part + ((size_t)blockIdx.y * NP + p) * LLEN + t) =
        make_float4(acc[0], acc[1], acc[2], acc[3]);
}

// =====================================================================
// fista_quad (round-5 version, measured ~2.6us): block = (itile, cquad, p).
//   staging: rs = y - sum_q part[q]  (reduce fused; first: rs = y)
//   g[c,i] = sum_k rs[i+k]*H[ch,c,k];  x_new = relu(B + g/LIP - thr)
// =====================================================================
__global__ __launch_bounds__(256) void fista_quad(
    const float* __restrict__ y, const float* __restrict__ part,
    const float* __restrict__ H,
    const float* __restrict__ Acur, const float* __restrict__ Aprev,
    float gamma, int first, float* __restrict__ Anext)
{
    __shared__ __align__(16) float rs[XW4 * 4];
    __shared__ __align__(16) float hs[4 * KS];
    const int tid = threadIdx.x;
    const int i0  = blockIdx.x * 1024;
    const int c0  = blockIdx.y * 4;
    const int p   = blockIdx.z;
    const int n = p & 15, ch = p >> 4;

    if (tid < 64)
        ((float4*)hs)[tid] = ((const float4*)(H + ((size_t)ch * CK + c0) * KS))[tid];

    const float* ybase = y + ((size_t)n * YCH + ch) * LLEN;
    #pragma unroll
    for (int s = 0; s < 2; ++s) {
        int l4 = tid + 256 * s;
        if (l4 < XW4) {
            int gi4 = i0 + 4 * l4;
            float4 v;
            if (gi4 + 3 < LLEN) {
                v = *(const float4*)(ybase + gi4);
                if (!first) {
                    #pragma unroll
                    for (int q = 0; q < 4; ++q) {
                        float4 pv = *(const float4*)(part + ((size_t)q * NP + p) * LLEN + gi4);
                        v.x -= pv.x; v.y -= pv.y; v.z -= pv.z; v.w -= pv.w;
                    }
                }
            } else {
                float r[4];
                #pragma unroll
                for (int j = 0; j < 4; ++j) {
                    int gi = gi4 + j;
                    if (gi < LLEN) {
                        float t = ybase[gi];
                        if (!first) {
                            #pragma unroll
                            for (int q = 0; q < 4; ++q)
                                t -= part[((size_t)q * NP + p) * LLEN + gi];
                        }
                        r[j] = t;
                    } else r[j] = 0.f;
                }
                v = make_float4(r[0], r[1], r[2], r[3]);
            }
            ((float4*)rs)[l4] = v;
        }
    }
    __syncthreads();

    // hoisted register window rs[4*tid .. 4*tid+67], shared by 4 channels
    float wf[68];
    const float4* rr = (const float4*)rs + tid;
    #pragma unroll
    for (int q = 0; q < 17; ++q) {
        float4 t4 = rr[q];
        wf[4*q] = t4.x; wf[4*q+1] = t4.y; wf[4*q+2] = t4.z; wf[4*q+3] = t4.w;
    }

    const int i = i0 + 4 * tid;
    const size_t pb = (size_t)p * CK * ENC;
    const bool vec = (i + 3 < ENC);

    float4 a0 = make_float4(0,0,0,0), p0 = make_float4(0,0,0,0);
    if (!first && vec) {
        a0 = *(const float4*)(Acur  + pb + (size_t)c0 * ENC + i);
        p0 = *(const float4*)(Aprev + pb + (size_t)c0 * ENC + i);
    }

    for (int cc = 0; cc < 4; ++cc) {
        float4 a1 = make_float4(0,0,0,0), p1 = make_float4(0,0,0,0);
        if (!first && vec && cc < 3) {
            a1 = *(const float4*)(Acur  + pb + (size_t)(c0 + cc + 1) * ENC + i);
            p1 = *(const float4*)(Aprev + pb + (size_t)(c0 + cc + 1) * ENC + i);
        }

        float acc[4] = {0.f, 0.f, 0.f, 0.f};
        const float4* hc = (const float4*)(hs + cc * KS);
        #pragma unroll
        for (int g = 0; g < 16; ++g) {
            float4 h4 = hc[g];
            float hh[4] = {h4.x, h4.y, h4.z, h4.w};
            #pragma unroll
            for (int m = 0; m < 4; ++m) {
                const int k = 4 * g + m;
                #pragma unroll
                for (int j = 0; j < 4; ++j)
                    acc[j] = fmaf(wf[k + j], hh[m], acc[j]);
            }
        }

        const size_t idx = pb + (size_t)(c0 + cc) * ENC + i;
        if (vec) {
            float B[4] = {0.f, 0.f, 0.f, 0.f};
            if (!first) {
                float av[4] = {a0.x, a0.y, a0.z, a0.w};
                float pv[4] = {p0.x, p0.y, p0.z, p0.w};
                #pragma unroll
                for (int j = 0; j < 4; ++j) B[j] = fmaf(gamma, av[j] - pv[j], av[j]);
            }
            float4 o;
            o.x = fmaxf(fmaf(acc[0], INV_LIP, B[0]) - THRESH, 0.f);
            o.y = fmaxf(fmaf(acc[1], INV_LIP, B[1]) - THRESH, 0.f);
            o.z = fmaxf(fmaf(acc[2], INV_LIP, B[2]) - THRESH, 0.f);
            o.w = fmaxf(fmaf(acc[3], INV_LIP, B[3]) - THRESH, 0.f);
            *(float4*)(Anext + idx) = o;
        } else if (i < ENC) {
            #pragma unroll
            for (int j = 0; j < 4; ++j) {
                if (i + j < ENC) {
                    float B = 0.f;
                    if (!first) {
                        float a = Acur[idx + j], pp = Aprev[idx + j];
                        B = fmaf(gamma, a - pp, a);
                    }
                    Anext[idx + j] = fmaxf(fmaf(acc[j], INV_LIP, B) - THRESH, 0.f);
                }
            }
        }
        a0 = a1; p0 = p1;
    }
}

// =====================================================================
extern "C" void kernel_launch(void* const* d_in, const int* in_sizes, int n_in,
                              void* d_out, int out_size, void* d_ws, size_t ws_size,
                              hipStream_t stream)
{
    const float* y = (const float*)d_in[0];   // [NTR, YCH, LLEN]
    const float* H = (const float*)d_in[1];   // [YCH, CK, 1, KS]
    const size_t XSZ = (size_t)NP * CK * ENC; // 8,259,584 floats

    float* bufA = (float*)d_ws;               // A_t for even t
    float* bufB = (float*)d_out;              // A_t for odd t (A9 -> d_out)
    float* part = bufA + XSZ;                 // [4][NP][LLEN] partial synth sums

    double s[11]; s[0] = 1.0;
    for (int t = 1; t <= 10; ++t) s[t] = 0.5 * (1.0 + sqrt(1.0 + 4.0 * s[t-1] * s[t-1]));

    dim3 gR(4, 4, NP), gF(4, 4, NP);

    for (int t = 0; t < 10; ++t) {
        float gamma = (t == 0) ? 0.f : (float)((s[t-1] - 1.0) / s[t]);
        float* Anext       = (t & 1) ? bufB : bufA;
        const float* Acur  = (t & 1) ? bufA : bufB;              // A_{t-1}
        const float* Aprev = (t <= 1) ? Acur                     // gamma==0, unused
                                      : ((t & 1) ? bufB : bufA); // A_{t-2}
        if (t == 0) {
            // B_0 = 0 => res = y; fuse into update kernel (first=1)
            fista_quad<<<gF, 256, 0, stream>>>(y, part, H, bufA, bufA, 0.f, 1, bufA);
        } else {
            resid_quad<<<gR, 256, 0, stream>>>(H, Acur, Aprev, gamma, part);
            fista_quad<<<gF, 256, 0, stream>>>(y, part, H, Acur, Aprev, gamma, 0, Anext);
        }
    }
}